// Round 1
// baseline (1894.713 us; speedup 1.0000x reference)
//
#include <hip/hip_runtime.h>
#include <hip/hip_bf16.h>

#define N1C 20000
#define N2C 20000
#define NC  40000           // N1C + N2C
#define EC  160000
#define ETC 480000          // 3*EC
#define CINC 128
#define HIDC 64
#define HC 4

// ---------- helpers ----------

// order-preserving float->uint encoding for atomicMax
__device__ __forceinline__ unsigned enc_f32(float f){
  unsigned u = __float_as_uint(f);
  return (u & 0x80000000u) ? ~u : (u | 0x80000000u);
}
__device__ __forceinline__ float dec_f32(unsigned u){
  unsigned v = (u & 0x80000000u) ? (u & 0x7FFFFFFFu) : ~u;
  return __uint_as_float(v);
}

// decode edge e of the concatenated edge list into (src,dst)
__device__ __forceinline__ void edge_sd(int e, const int* __restrict__ ei1,
                                        const int* __restrict__ ei2, int& s, int& d){
  if (e < EC)            { s = ei1[e];           d = ei1[EC + e]; }
  else if (e < 2*EC)     { int t = e - EC;   s = ei2[t] + N1C;  d = ei2[EC + t] + N1C; }
  else                   { int t = e - 2*EC; s = ei1[t] + N1C;  d = ei1[EC + t] + N1C; }
}

// ---------- kernels ----------

__global__ void concat_x(const float* __restrict__ x1, const float* __restrict__ x2,
                         float* __restrict__ X){
  int i = blockIdx.x*256 + threadIdx.x;
  if (i >= NC*CINC) return;
  int n = i / CINC, c = i - n*CINC;
  X[i] = (n < N1C) ? x1[i] : x2[(n - N1C)*CINC + c];
}

// row-blocked GEMM: Hout[n, m] = sum_k X[n,k] * W[k,m]; 8 rows per block, 256 threads
template<int K, int M>
__global__ void gemm_rows(const float* __restrict__ X, const float* __restrict__ W,
                          float* __restrict__ Hout, int nrows){
  __shared__ float xs[8][K];
  const int n0 = blockIdx.x * 8;
  const int tid = threadIdx.x;
  for (int i = tid; i < 8*K; i += 256){
    int r = i / K, c = i - r*K;
    int n = n0 + r;
    xs[r][c] = (n < nrows) ? X[(long)n*K + c] : 0.f;
  }
  __syncthreads();
  constexpr int MPT = (M + 255)/256;
  float acc[8][MPT];
  #pragma unroll
  for (int r = 0; r < 8; ++r)
    #pragma unroll
    for (int j = 0; j < MPT; ++j) acc[r][j] = 0.f;

  for (int k = 0; k < K; ++k){
    float w[MPT];
    #pragma unroll
    for (int j = 0; j < MPT; ++j){
      int col = tid + j*256;
      w[j] = (col < M) ? W[k*M + col] : 0.f;
    }
    #pragma unroll
    for (int r = 0; r < 8; ++r){
      float xv = xs[r][k];
      #pragma unroll
      for (int j = 0; j < MPT; ++j) acc[r][j] += xv * w[j];
    }
  }
  #pragma unroll
  for (int r = 0; r < 8; ++r){
    int n = n0 + r;
    if (n >= nrows) continue;
    #pragma unroll
    for (int j = 0; j < MPT; ++j){
      int col = tid + j*256;
      if (col < M) Hout[(long)n*M + col] = acc[r][j];
    }
  }
}

// AS[n,h] = sum_c H[n,h,c]*att_s[h,c]; AD likewise
template<int C>
__global__ void att_scores(const float* __restrict__ H, const float* __restrict__ att_s,
                           const float* __restrict__ att_d, float* __restrict__ AS,
                           float* __restrict__ AD){
  int i = blockIdx.x*256 + threadIdx.x;       // i = n*HC + h
  if (i >= NC*HC) return;
  int n = i / HC, h = i - n*HC;
  const float* hp = H + (long)n*(HC*C) + h*C;
  const float* sp = att_s + h*C;
  const float* dp = att_d + h*C;
  float as = 0.f, ad = 0.f;
  for (int c = 0; c < C; ++c){ float v = hp[c]; as += v*sp[c]; ad += v*dp[c]; }
  AS[i] = as; AD[i] = ad;
}

__global__ void edge_max_k(const int* __restrict__ ei1, const int* __restrict__ ei2,
                           const float* __restrict__ AS, const float* __restrict__ AD,
                           unsigned* __restrict__ EMAX){
  int e = blockIdx.x*256 + threadIdx.x;
  if (e >= ETC) return;
  int s, d; edge_sd(e, ei1, ei2, s, d);
  #pragma unroll
  for (int h = 0; h < HC; ++h){
    float v = AS[s*HC + h] + AD[d*HC + h];
    v = (v > 0.f) ? v : 0.2f*v;
    atomicMax(&EMAX[d*HC + h], enc_f32(v));
  }
}

__global__ void edge_exp_k(const int* __restrict__ ei1, const int* __restrict__ ei2,
                           const float* __restrict__ AS, const float* __restrict__ AD,
                           const unsigned* __restrict__ EMAX, float* __restrict__ EEXP,
                           float* __restrict__ DEN){
  int e = blockIdx.x*256 + threadIdx.x;
  if (e >= ETC) return;
  int s, d; edge_sd(e, ei1, ei2, s, d);
  #pragma unroll
  for (int h = 0; h < HC; ++h){
    float v = AS[s*HC + h] + AD[d*HC + h];
    v = (v > 0.f) ? v : 0.2f*v;
    float p = expf(v - dec_f32(EMAX[d*HC + h]));
    EEXP[e*HC + h] = p;
    atomicAdd(&DEN[d*HC + h], p);
  }
}

// one wave (64 lanes) per edge; lane covers channel(s); mean over heads folded in (0.25)
template<int C>
__global__ void edge_msg_k(const int* __restrict__ ei1, const int* __restrict__ ei2,
                           const float* __restrict__ EEXP, const float* __restrict__ DEN,
                           const float* __restrict__ H, float* __restrict__ OUT){
  int lane = threadIdx.x & 63;
  int widx = threadIdx.x >> 6;
  int e = blockIdx.x*4 + widx;
  if (e >= ETC) return;
  int s, d; edge_sd(e, ei1, ei2, s, d);
  float alpha[HC];
  #pragma unroll
  for (int h = 0; h < HC; ++h)
    alpha[h] = EEXP[e*HC + h] / (DEN[d*HC + h] + 1e-16f) * 0.25f;
  const float* hs = H + (long)s*(HC*C);
  float* od = OUT + (long)d*C;
  #pragma unroll
  for (int j = 0; j < C/64; ++j){
    int c = lane + j*64;
    float acc = 0.f;
    #pragma unroll
    for (int h = 0; h < HC; ++h) acc += alpha[h]*hs[h*C + c];
    atomicAdd(&od[c], acc);
  }
}

template<int C, bool RELU>
__global__ void finalize_k(const float* __restrict__ OUT, const float* __restrict__ bias,
                           float* __restrict__ Xn){
  int i = blockIdx.x*256 + threadIdx.x;
  if (i >= NC*C) return;
  int c = i % C;
  float v = OUT[i] + bias[c];
  if (RELU) v = fmaxf(v, 0.f);
  Xn[i] = v;
}

// per output row: L2-normalize h2 row, add residual (incl. bres)
__global__ void final_out_k(const float* __restrict__ Hfin, const float* __restrict__ RES,
                            const float* __restrict__ bres, float* __restrict__ out){
  int n = blockIdx.x;
  int lane = threadIdx.x;  // 64
  const float* hp = Hfin + (long)(N1C + n)*CINC;
  float v0 = hp[lane];
  float v1 = hp[lane + 64];
  float ss = v0*v0 + v1*v1;
  #pragma unroll
  for (int off = 32; off; off >>= 1) ss += __shfl_xor(ss, off);
  float inv = 1.f / fmaxf(sqrtf(ss), 1e-12f);
  float* op = out + (long)n*CINC;
  op[lane]      = v0*inv + RES[(long)n*CINC + lane]      + bres[lane];
  op[lane + 64] = v1*inv + RES[(long)n*CINC + lane + 64] + bres[lane + 64];
}

// ---------- launch ----------

extern "C" void kernel_launch(void* const* d_in, const int* in_sizes, int n_in,
                              void* d_out, int out_size, void* d_ws, size_t ws_size,
                              hipStream_t stream) {
  const float* x1  = (const float*)d_in[0];
  const float* x2  = (const float*)d_in[1];
  const int*   ei1 = (const int*)  d_in[2];
  const int*   ei2 = (const int*)  d_in[3];
  const float* W0  = (const float*)d_in[4];
  const float* a0s = (const float*)d_in[5];
  const float* a0d = (const float*)d_in[6];
  const float* b0  = (const float*)d_in[7];
  const float* W1  = (const float*)d_in[8];
  const float* a1s = (const float*)d_in[9];
  const float* a1d = (const float*)d_in[10];
  const float* b1  = (const float*)d_in[11];
  const float* W2  = (const float*)d_in[12];
  const float* a2s = (const float*)d_in[13];
  const float* a2d = (const float*)d_in[14];
  const float* b2  = (const float*)d_in[15];
  const float* Wf  = (const float*)d_in[16];
  const float* afs = (const float*)d_in[17];
  const float* afd = (const float*)d_in[18];
  const float* bf  = (const float*)d_in[19];
  const float* Wres= (const float*)d_in[20];
  const float* bres= (const float*)d_in[21];
  float* out = (float*)d_out;

  char* ws = (char*)d_ws;
  float*    Xa   = (float*)   (ws + 0);           // N*128 f32 = 20,480,000 B
  float*    Xb   = (float*)   (ws + 20480000);    // N*128 f32
  float*    H    = (float*)   (ws + 40960000);    // N*512 f32 = 81,920,000 B
  float*    OUT  = (float*)   (ws + 122880000);   // N*128 f32
  float*    AS   = (float*)   (ws + 143360000);   // N*4 f32 = 640,000 B
  float*    AD   = (float*)   (ws + 144000000);
  unsigned* EMAX = (unsigned*)(ws + 144640000);
  float*    DEN  = (float*)   (ws + 145280000);
  float*    EEXP = (float*)   (ws + 145920000);   // 3E*4 f32 = 7,680,000 B
  float*    RES  = (float*)   (ws + 153600000);   // 20000*128 f32 = 10,240,000 B
  // total 163,840,000 B

  const int EG = (ETC + 255)/256;       // edge-parallel grids
  const int MG = (ETC + 3)/4;           // wave-per-edge grid

  // concat inputs -> Xa (f32)
  concat_x<<<(NC*CINC + 255)/256, 256, 0, stream>>>(x1, x2, Xa);

  // residual = x2 @ Wres (bres added at the end)
  gemm_rows<128,128><<<(N2C + 7)/8, 256, 0, stream>>>(x2, Wres, RES, N2C);

  // ---- layer 0: K=128, M=256, C=64, relu ----
  gemm_rows<128,256><<<(NC + 7)/8, 256, 0, stream>>>(Xa, W0, H, NC);
  att_scores<64><<<(NC*HC + 255)/256, 256, 0, stream>>>(H, a0s, a0d, AS, AD);
  hipMemsetAsync(EMAX, 0, NC*HC*4, stream);
  hipMemsetAsync(DEN,  0, NC*HC*4, stream);
  hipMemsetAsync(OUT,  0, NC*64*4, stream);
  edge_max_k<<<EG, 256, 0, stream>>>(ei1, ei2, AS, AD, EMAX);
  edge_exp_k<<<EG, 256, 0, stream>>>(ei1, ei2, AS, AD, EMAX, EEXP, DEN);
  edge_msg_k<64><<<MG, 256, 0, stream>>>(ei1, ei2, EEXP, DEN, H, OUT);
  finalize_k<64,true><<<(NC*64 + 255)/256, 256, 0, stream>>>(OUT, b0, Xb);

  // ---- layer 1: K=64, M=256, C=64, relu ----
  gemm_rows<64,256><<<(NC + 7)/8, 256, 0, stream>>>(Xb, W1, H, NC);
  att_scores<64><<<(NC*HC + 255)/256, 256, 0, stream>>>(H, a1s, a1d, AS, AD);
  hipMemsetAsync(EMAX, 0, NC*HC*4, stream);
  hipMemsetAsync(DEN,  0, NC*HC*4, stream);
  hipMemsetAsync(OUT,  0, NC*64*4, stream);
  edge_max_k<<<EG, 256, 0, stream>>>(ei1, ei2, AS, AD, EMAX);
  edge_exp_k<<<EG, 256, 0, stream>>>(ei1, ei2, AS, AD, EMAX, EEXP, DEN);
  edge_msg_k<64><<<MG, 256, 0, stream>>>(ei1, ei2, EEXP, DEN, H, OUT);
  finalize_k<64,true><<<(NC*64 + 255)/256, 256, 0, stream>>>(OUT, b1, Xa);

  // ---- layer 2: K=64, M=512, C=128, relu ----
  gemm_rows<64,512><<<(NC + 7)/8, 256, 0, stream>>>(Xa, W2, H, NC);
  att_scores<128><<<(NC*HC + 255)/256, 256, 0, stream>>>(H, a2s, a2d, AS, AD);
  hipMemsetAsync(EMAX, 0, NC*HC*4, stream);
  hipMemsetAsync(DEN,  0, NC*HC*4, stream);
  hipMemsetAsync(OUT,  0, NC*128*4, stream);
  edge_max_k<<<EG, 256, 0, stream>>>(ei1, ei2, AS, AD, EMAX);
  edge_exp_k<<<EG, 256, 0, stream>>>(ei1, ei2, AS, AD, EMAX, EEXP, DEN);
  edge_msg_k<128><<<MG, 256, 0, stream>>>(ei1, ei2, EEXP, DEN, H, OUT);
  finalize_k<128,true><<<(NC*128 + 255)/256, 256, 0, stream>>>(OUT, b2, Xb);

  // ---- layer f: K=128, M=512, C=128, no relu ----
  gemm_rows<128,512><<<(NC + 7)/8, 256, 0, stream>>>(Xb, Wf, H, NC);
  att_scores<128><<<(NC*HC + 255)/256, 256, 0, stream>>>(H, afs, afd, AS, AD);
  hipMemsetAsync(EMAX, 0, NC*HC*4, stream);
  hipMemsetAsync(DEN,  0, NC*HC*4, stream);
  hipMemsetAsync(OUT,  0, NC*128*4, stream);
  edge_max_k<<<EG, 256, 0, stream>>>(ei1, ei2, AS, AD, EMAX);
  edge_exp_k<<<EG, 256, 0, stream>>>(ei1, ei2, AS, AD, EMAX, EEXP, DEN);
  edge_msg_k<128><<<MG, 256, 0, stream>>>(ei1, ei2, EEXP, DEN, H, OUT);
  finalize_k<128,false><<<(NC*128 + 255)/256, 256, 0, stream>>>(OUT, bf, Xa);

  // ---- output: norm(h2) + x2@Wres + bres ----
  final_out_k<<<N2C, 64, 0, stream>>>(Xa, RES, bres, out);
}

// Round 2
// 982.196 us; speedup vs baseline: 1.9291x; 1.9291x over previous
//
#include <hip/hip_runtime.h>
#include <hip/hip_bf16.h>

#define N1C 20000
#define N2C 20000
#define NC  40000           // N1C + N2C
#define EC  160000
#define ETC 480000          // 3*EC
#define CINC 128
#define HC 4

// decode edge e of the concatenated edge list into (src,dst)
__device__ __forceinline__ void edge_sd(int e, const int* __restrict__ ei1,
                                        const int* __restrict__ ei2, int& s, int& d){
  if (e < EC)            { s = ei1[e];           d = ei1[EC + e]; }
  else if (e < 2*EC)     { int t = e - EC;   s = ei2[t] + N1C;  d = ei2[EC + t] + N1C; }
  else                   { int t = e - 2*EC; s = ei1[t] + N1C;  d = ei1[EC + t] + N1C; }
}

__device__ __forceinline__ float4 leaky4(float4 v){
  v.x = v.x > 0.f ? v.x : 0.2f*v.x;
  v.y = v.y > 0.f ? v.y : 0.2f*v.y;
  v.z = v.z > 0.f ? v.z : 0.2f*v.z;
  v.w = v.w > 0.f ? v.w : 0.2f*v.w;
  return v;
}

// ---------- kernels ----------

__global__ void concat_x(const float* __restrict__ x1, const float* __restrict__ x2,
                         float* __restrict__ X){
  int i = blockIdx.x*256 + threadIdx.x;
  if (i >= NC*CINC) return;
  X[i] = (i < N1C*CINC) ? x1[i] : x2[i - N1C*CINC];
}

// permute W columns: Wp[k][c*4+h] = W[k][h*C+c]   (M = 4*C)
__global__ void permW_k(const float* __restrict__ W, float* __restrict__ Wp, int K, int C){
  int M = 4*C;
  int i = blockIdx.x*256 + threadIdx.x;
  if (i >= K*M) return;
  int k = i / M, r = i - k*M;
  int c = r >> 2, h = r & 3;
  Wp[i] = W[k*M + h*C + c];
}

// row-blocked GEMM: Hout[n, m] = sum_k X[n,k] * W[k,m]; 8 rows per block, 256 threads
template<int K, int M>
__global__ void gemm_rows(const float* __restrict__ X, const float* __restrict__ W,
                          float* __restrict__ Hout, int nrows){
  __shared__ float xs[8][K];
  const int n0 = blockIdx.x * 8;
  const int tid = threadIdx.x;
  for (int i = tid; i < 8*K; i += 256){
    int r = i / K, c = i - r*K;
    int n = n0 + r;
    xs[r][c] = (n < nrows) ? X[(long)n*K + c] : 0.f;
  }
  __syncthreads();
  constexpr int MPT = (M + 255)/256;
  float acc[8][MPT];
  #pragma unroll
  for (int r = 0; r < 8; ++r)
    #pragma unroll
    for (int j = 0; j < MPT; ++j) acc[r][j] = 0.f;

  for (int k = 0; k < K; ++k){
    float w[MPT];
    #pragma unroll
    for (int j = 0; j < MPT; ++j){
      int col = tid + j*256;
      w[j] = (col < M) ? W[k*M + col] : 0.f;
    }
    #pragma unroll
    for (int r = 0; r < 8; ++r){
      float xv = xs[r][k];
      #pragma unroll
      for (int j = 0; j < MPT; ++j) acc[r][j] += xv * w[j];
    }
  }
  #pragma unroll
  for (int r = 0; r < 8; ++r){
    int n = n0 + r;
    if (n >= nrows) continue;
    #pragma unroll
    for (int j = 0; j < MPT; ++j){
      int col = tid + j*256;
      if (col < M) Hout[(long)n*M + col] = acc[r][j];
    }
  }
}

// AS[n,h] = sum_c H[n,c,h]*att_s[h,c]  (H in [n][c][h] layout)
template<int C>
__global__ void att_scores_perm(const float* __restrict__ H, const float* __restrict__ att_s,
                                const float* __restrict__ att_d, float* __restrict__ AS,
                                float* __restrict__ AD){
  int i = blockIdx.x*256 + threadIdx.x;       // i = n*HC + h
  if (i >= NC*HC) return;
  int n = i >> 2, h = i & 3;
  const float* hp = H + (long)n*(HC*C) + h;
  const float* sp = att_s + h*C;
  const float* dp = att_d + h*C;
  float as = 0.f, ad = 0.f;
  for (int c = 0; c < C; ++c){ float v = hp[c*4]; as += v*sp[c]; ad += v*dp[c]; }
  AS[i] = as; AD[i] = ad;
}

// ---------- CSR build ----------

__global__ void count_k(const int* __restrict__ ei1, const int* __restrict__ ei2,
                        int* __restrict__ CNT){
  int e = blockIdx.x*256 + threadIdx.x;
  if (e >= ETC) return;
  int s, d; edge_sd(e, ei1, ei2, s, d);
  atomicAdd(&CNT[d], 1);
}

__global__ __launch_bounds__(1024) void scan_k(const int* __restrict__ CNT,
                                               int* __restrict__ OFF, int* __restrict__ CUR){
  __shared__ int sums[1024];
  const int t = threadIdx.x;
  const int PER = (NC + 1023)/1024;   // 40
  const int base = t*PER;
  int local = 0;
  for (int i = 0; i < PER; ++i){ int idx = base + i; if (idx < NC) local += CNT[idx]; }
  sums[t] = local;
  __syncthreads();
  for (int off = 1; off < 1024; off <<= 1){
    int v = (t >= off) ? sums[t - off] : 0;
    __syncthreads();
    sums[t] += v;
    __syncthreads();
  }
  int run = (t == 0) ? 0 : sums[t-1];
  for (int i = 0; i < PER; ++i){
    int idx = base + i;
    if (idx < NC){ OFF[idx] = run; CUR[idx] = run; run += CNT[idx]; }
  }
  if (t == 1023) OFF[NC] = sums[1023];
}

__global__ void scatter_k(const int* __restrict__ ei1, const int* __restrict__ ei2,
                          int* __restrict__ CUR, int* __restrict__ ESRC){
  int e = blockIdx.x*256 + threadIdx.x;
  if (e >= ETC) return;
  int s, d; edge_sd(e, ei1, ei2, s, d);
  int pos = atomicAdd(&CUR[d], 1);
  ESRC[pos] = s;
}

// ---------- fused per-dst softmax + aggregation ----------
// H in [n][c][h] layout (float4 per (n,c)); one wave per dst node.
template<int C, bool RELU>
__global__ void agg_k(const int* __restrict__ OFF, const int* __restrict__ ESRC,
                      const float* __restrict__ AS, const float* __restrict__ AD,
                      const float* __restrict__ H, const float* __restrict__ bias,
                      float* __restrict__ Xout){
  __shared__ int    sm_s[4][64];
  __shared__ float4 sm_p[4][64];
  const int lane = threadIdx.x & 63;
  const int w    = threadIdx.x >> 6;
  const int d    = blockIdx.x*4 + w;     // NC divisible by 4, no bounds check
  const int beg = OFF[d], end = OFF[d+1];
  const float4 ad4 = ((const float4*)AD)[d];

  // pass 1: per-head max over incident edges (lane-parallel over edges)
  float4 m4 = make_float4(-1e30f, -1e30f, -1e30f, -1e30f);
  for (int i0 = beg; i0 < end; i0 += 64){
    int idx = i0 + lane;
    if (idx < end){
      int s = ESRC[idx];
      float4 a = ((const float4*)AS)[s];
      float4 sc = leaky4(make_float4(a.x+ad4.x, a.y+ad4.y, a.z+ad4.z, a.w+ad4.w));
      m4.x = fmaxf(m4.x, sc.x); m4.y = fmaxf(m4.y, sc.y);
      m4.z = fmaxf(m4.z, sc.z); m4.w = fmaxf(m4.w, sc.w);
    }
  }
  #pragma unroll
  for (int off = 32; off; off >>= 1){
    m4.x = fmaxf(m4.x, __shfl_xor(m4.x, off));
    m4.y = fmaxf(m4.y, __shfl_xor(m4.y, off));
    m4.z = fmaxf(m4.z, __shfl_xor(m4.z, off));
    m4.w = fmaxf(m4.w, __shfl_xor(m4.w, off));
  }

  // pass 2: exp weights + denominator + weighted gather of H rows
  constexpr int J = C/64;
  float4 den = make_float4(0.f,0.f,0.f,0.f);
  float4 acc[J];
  #pragma unroll
  for (int j = 0; j < J; ++j) acc[j] = make_float4(0.f,0.f,0.f,0.f);

  for (int i0 = beg; i0 < end; i0 += 64){
    int cnt = min(64, end - i0);
    if (lane < cnt){
      int s = ESRC[i0 + lane];
      float4 a = ((const float4*)AS)[s];
      float4 sc = leaky4(make_float4(a.x+ad4.x, a.y+ad4.y, a.z+ad4.z, a.w+ad4.w));
      float4 p = make_float4(__expf(sc.x - m4.x), __expf(sc.y - m4.y),
                             __expf(sc.z - m4.z), __expf(sc.w - m4.w));
      den.x += p.x; den.y += p.y; den.z += p.z; den.w += p.w;
      sm_s[w][lane] = s;
      sm_p[w][lane] = p;
    }
    __builtin_amdgcn_wave_barrier();   // order LDS write before same-wave cross-lane read
    #pragma unroll 2
    for (int e = 0; e < cnt; ++e){
      int s = sm_s[w][e];
      float4 p = sm_p[w][e];
      const float4* hrow = (const float4*)H + (long)s*C;
      #pragma unroll
      for (int j = 0; j < J; ++j){
        float4 hv = hrow[lane + j*64];
        acc[j].x += p.x*hv.x; acc[j].y += p.y*hv.y;
        acc[j].z += p.z*hv.z; acc[j].w += p.w*hv.w;
      }
    }
    __builtin_amdgcn_wave_barrier();
  }

  #pragma unroll
  for (int off = 32; off; off >>= 1){
    den.x += __shfl_xor(den.x, off);
    den.y += __shfl_xor(den.y, off);
    den.z += __shfl_xor(den.z, off);
    den.w += __shfl_xor(den.w, off);
  }
  float4 r = make_float4(1.f/(den.x + 1e-16f), 1.f/(den.y + 1e-16f),
                         1.f/(den.z + 1e-16f), 1.f/(den.w + 1e-16f));
  #pragma unroll
  for (int j = 0; j < J; ++j){
    int c = lane + j*64;
    float o = 0.25f*(acc[j].x*r.x + acc[j].y*r.y + acc[j].z*r.z + acc[j].w*r.w) + bias[c];
    if (RELU) o = fmaxf(o, 0.f);
    Xout[(long)d*C + c] = o;
  }
}

// per output row: L2-normalize h2 row, add residual (incl. bres)
__global__ void final_out_k(const float* __restrict__ Hfin, const float* __restrict__ RES,
                            const float* __restrict__ bres, float* __restrict__ out){
  int n = blockIdx.x;
  int lane = threadIdx.x;  // 64
  const float* hp = Hfin + (long)(N1C + n)*CINC;
  float v0 = hp[lane];
  float v1 = hp[lane + 64];
  float ss = v0*v0 + v1*v1;
  #pragma unroll
  for (int off = 32; off; off >>= 1) ss += __shfl_xor(ss, off);
  float inv = 1.f / fmaxf(sqrtf(ss), 1e-12f);
  float* op = out + (long)n*CINC;
  op[lane]      = v0*inv + RES[(long)n*CINC + lane]      + bres[lane];
  op[lane + 64] = v1*inv + RES[(long)n*CINC + lane + 64] + bres[lane + 64];
}

// ---------- launch ----------

extern "C" void kernel_launch(void* const* d_in, const int* in_sizes, int n_in,
                              void* d_out, int out_size, void* d_ws, size_t ws_size,
                              hipStream_t stream) {
  const float* x1  = (const float*)d_in[0];
  const float* x2  = (const float*)d_in[1];
  const int*   ei1 = (const int*)  d_in[2];
  const int*   ei2 = (const int*)  d_in[3];
  const float* W0  = (const float*)d_in[4];
  const float* a0s = (const float*)d_in[5];
  const float* a0d = (const float*)d_in[6];
  const float* b0  = (const float*)d_in[7];
  const float* W1  = (const float*)d_in[8];
  const float* a1s = (const float*)d_in[9];
  const float* a1d = (const float*)d_in[10];
  const float* b1  = (const float*)d_in[11];
  const float* W2  = (const float*)d_in[12];
  const float* a2s = (const float*)d_in[13];
  const float* a2d = (const float*)d_in[14];
  const float* b2  = (const float*)d_in[15];
  const float* Wf  = (const float*)d_in[16];
  const float* afs = (const float*)d_in[17];
  const float* afd = (const float*)d_in[18];
  const float* bf  = (const float*)d_in[19];
  const float* Wres= (const float*)d_in[20];
  const float* bres= (const float*)d_in[21];
  float* out = (float*)d_out;

  char* ws = (char*)d_ws;
  float* Xa   = (float*)(ws + 0);             // N*128 f32 = 20,480,000 B
  float* Xb   = (float*)(ws + 20480000);      // N*128 f32
  float* H    = (float*)(ws + 40960000);      // N*512 f32 = 81,920,000 B
  float* RES  = (float*)(ws + 122880000);     // 20000*128 f32 = 10,240,000 B
  float* AS   = (float*)(ws + 133120000);     // N*4 f32 = 640,000 B
  float* AD   = (float*)(ws + 133760000);
  int*   OFF  = (int*)  (ws + 134400000);     // (N+1) ints
  int*   CUR  = (int*)  (ws + 134560064);     // N ints
  int*   ESRC = (int*)  (ws + 134720064);     // 3E ints = 1,920,000 B
  float* W0p  = (float*)(ws + 136640064);     // 131,072 B
  float* W1p  = (float*)(ws + 136771136);     //  65,536 B
  float* W2p  = (float*)(ws + 136836672);     // 131,072 B
  float* Wfp  = (float*)(ws + 136967744);     // 262,144 B
  int*   CNT  = (int*)  (ws + 137229888);     // N ints
  // total ≈ 137.4 MB

  const int EG = (ETC + 255)/256;

  // concat inputs -> Xa
  concat_x<<<(NC*CINC + 255)/256, 256, 0, stream>>>(x1, x2, Xa);

  // CSR build (once per call)
  hipMemsetAsync(CNT, 0, NC*4, stream);
  count_k<<<EG, 256, 0, stream>>>(ei1, ei2, CNT);
  scan_k<<<1, 1024, 0, stream>>>(CNT, OFF, CUR);
  scatter_k<<<EG, 256, 0, stream>>>(ei1, ei2, CUR, ESRC);

  // permuted weights (H layout [n][c][h])
  permW_k<<<(128*256 + 255)/256, 256, 0, stream>>>(W0, W0p, 128, 64);
  permW_k<<<( 64*256 + 255)/256, 256, 0, stream>>>(W1, W1p,  64, 64);
  permW_k<<<( 64*512 + 255)/256, 256, 0, stream>>>(W2, W2p,  64, 128);
  permW_k<<<(128*512 + 255)/256, 256, 0, stream>>>(Wf, Wfp, 128, 128);

  // residual = x2 @ Wres (bres added at the end)
  gemm_rows<128,128><<<(N2C + 7)/8, 256, 0, stream>>>(x2, Wres, RES, N2C);

  // ---- layer 0: K=128, C=64, relu ----
  gemm_rows<128,256><<<(NC + 7)/8, 256, 0, stream>>>(Xa, W0p, H, NC);
  att_scores_perm<64><<<(NC*HC + 255)/256, 256, 0, stream>>>(H, a0s, a0d, AS, AD);
  agg_k<64,true><<<NC/4, 256, 0, stream>>>(OFF, ESRC, AS, AD, H, b0, Xb);

  // ---- layer 1: K=64, C=64, relu ----
  gemm_rows<64,256><<<(NC + 7)/8, 256, 0, stream>>>(Xb, W1p, H, NC);
  att_scores_perm<64><<<(NC*HC + 255)/256, 256, 0, stream>>>(H, a1s, a1d, AS, AD);
  agg_k<64,true><<<NC/4, 256, 0, stream>>>(OFF, ESRC, AS, AD, H, b1, Xa);

  // ---- layer 2: K=64, C=128, relu ----
  gemm_rows<64,512><<<(NC + 7)/8, 256, 0, stream>>>(Xa, W2p, H, NC);
  att_scores_perm<128><<<(NC*HC + 255)/256, 256, 0, stream>>>(H, a2s, a2d, AS, AD);
  agg_k<128,true><<<NC/4, 256, 0, stream>>>(OFF, ESRC, AS, AD, H, b2, Xb);

  // ---- layer f: K=128, C=128, no relu ----
  gemm_rows<128,512><<<(NC + 7)/8, 256, 0, stream>>>(Xb, Wfp, H, NC);
  att_scores_perm<128><<<(NC*HC + 255)/256, 256, 0, stream>>>(H, afs, afd, AS, AD);
  agg_k<128,false><<<NC/4, 256, 0, stream>>>(OFF, ESRC, AS, AD, H, bf, Xa);

  // ---- output: norm(h2) + x2@Wres + bres ----
  final_out_k<<<N2C, 64, 0, stream>>>(Xa, RES, bres, out);
}

// Round 3
// 633.950 us; speedup vs baseline: 2.9887x; 1.5493x over previous
//
#include <hip/hip_runtime.h>
#include <hip/hip_bf16.h>
#include <string.h>

#define N1C 20000
#define N2C 20000
#define NC  40000           // N1C + N2C
#define EC  160000
#define ETC 480000          // 3*EC
#define CINC 128
#define HC 4

typedef __attribute__((ext_vector_type(8))) short short8v;
typedef __attribute__((ext_vector_type(4))) float f32x4;

__device__ __forceinline__ ushort f2bu(float f){
  __hip_bfloat16 h = __float2bfloat16(f);
  union { __hip_bfloat16 b; ushort u; } v; v.b = h; return v.u;
}
__device__ __forceinline__ float b2f(ushort u){
  return __uint_as_float(((unsigned)u) << 16);
}

// decode edge e of the concatenated edge list into (src,dst)
__device__ __forceinline__ void edge_sd(int e, const int* __restrict__ ei1,
                                        const int* __restrict__ ei2, int& s, int& d){
  if (e < EC)            { s = ei1[e];           d = ei1[EC + e]; }
  else if (e < 2*EC)     { int t = e - EC;   s = ei2[t] + N1C;  d = ei2[EC + t] + N1C; }
  else                   { int t = e - 2*EC; s = ei1[t] + N1C;  d = ei1[EC + t] + N1C; }
}

__device__ __forceinline__ float4 leaky4(float4 v){
  v.x = v.x > 0.f ? v.x : 0.2f*v.x;
  v.y = v.y > 0.f ? v.y : 0.2f*v.y;
  v.z = v.z > 0.f ? v.z : 0.2f*v.z;
  v.w = v.w > 0.f ? v.w : 0.2f*v.w;
  return v;
}

// ---------- input prep ----------

__global__ void concat_x(const float* __restrict__ x1, const float* __restrict__ x2,
                         ushort* __restrict__ X){
  int i = blockIdx.x*256 + threadIdx.x;
  if (i >= NC*CINC) return;
  float v = (i < N1C*CINC) ? x1[i] : x2[i - N1C*CINC];
  X[i] = f2bu(v);
}

// Wt[m][k] (bf16) = W[k][perm(m)]; perm(m) = (m&3)*Ch + (m>>2) if Ch>0 else m
__global__ void permW_k(const float* __restrict__ W, ushort* __restrict__ Wt,
                        int K, int M, int Ch){
  int i = blockIdx.x*256 + threadIdx.x;
  if (i >= K*M) return;
  int m = i / K, k = i - m*K;
  int col = Ch ? ((m & 3)*Ch + (m >> 2)) : m;
  Wt[i] = f2bu(W[k*M + col]);
}

// ---------- MFMA GEMM: H[n][m] = sum_k X[n][k] * Wt[m][k]; bf16 in, bf16/f32 out ----------
// block 256 = 4 waves; wave w: rows n0+16w..+16, cols m0..m0+64; grid (ceil(n/64), M/64)
template<int K, bool F32OUT>
__global__ __launch_bounds__(256)
void gemm_mfma(const ushort* __restrict__ X, const ushort* __restrict__ Wt,
               ushort* __restrict__ Hout, float* __restrict__ HoutF, int nrows, int M){
  __shared__ float st[4][16][68];
  const int lane = threadIdx.x & 63;
  const int w    = threadIdx.x >> 6;
  const int n0   = blockIdx.x*64 + w*16;
  const int m0   = blockIdx.y*64;
  const int hi = lane >> 4;      // 0..3
  const int lo = lane & 15;      // 0..15
  int ra = n0 + lo; if (ra >= nrows) ra = nrows - 1;   // clamp (load safety)
  const ushort* ap = X + (long)ra*K + hi*8;

  f32x4 acc[4];
  #pragma unroll
  for (int t = 0; t < 4; ++t) acc[t] = (f32x4){0.f,0.f,0.f,0.f};

  #pragma unroll
  for (int k0 = 0; k0 < K; k0 += 32){
    short8v a = *(const short8v*)(ap + k0);
    #pragma unroll
    for (int t = 0; t < 4; ++t){
      short8v b = *(const short8v*)(Wt + (long)(m0 + t*16 + lo)*K + k0 + hi*8);
      acc[t] = __builtin_amdgcn_mfma_f32_16x16x32_bf16(a, b, acc[t], 0, 0, 0);
    }
  }
  // stage f32 tile: D row=(hi*4+j), col=t*16+lo
  #pragma unroll
  for (int t = 0; t < 4; ++t)
    #pragma unroll
    for (int j = 0; j < 4; ++j)
      st[w][hi*4 + j][t*16 + lo] = acc[t][j];
  __builtin_amdgcn_wave_barrier();

  const int row = lane >> 2, cg = lane & 3;
  if (n0 + row < nrows){
    if (F32OUT){
      float* op = HoutF + (long)(n0 + row)*M + m0 + cg*16;
      #pragma unroll
      for (int q = 0; q < 4; ++q)
        *(float4*)(op + q*4) = *(float4*)&st[w][row][cg*16 + q*4];
    } else {
      ushort* op = Hout + (long)(n0 + row)*M + m0 + cg*16;
      #pragma unroll
      for (int q = 0; q < 4; ++q){
        float4 v = *(float4*)&st[w][row][cg*16 + q*4];
        ushort4 u; u.x = f2bu(v.x); u.y = f2bu(v.y); u.z = f2bu(v.z); u.w = f2bu(v.w);
        *(ushort4*)(op + q*4) = u;
      }
    }
  }
}

// AS[n,h] = sum_c H[n,c,h]*att_s[h,c]  (H bf16 in [n][c][h] layout)
template<int C>
__global__ void att_scores_perm(const ushort* __restrict__ H16, const float* __restrict__ att_s,
                                const float* __restrict__ att_d, float* __restrict__ AS,
                                float* __restrict__ AD){
  int i = blockIdx.x*256 + threadIdx.x;       // i = n*HC + h
  if (i >= NC*HC) return;
  int n = i >> 2, h = i & 3;
  const ushort* hp = H16 + (long)n*(HC*C) + h;
  const float* sp = att_s + h*C;
  const float* dp = att_d + h*C;
  float as = 0.f, ad = 0.f;
  for (int c = 0; c < C; ++c){ float v = b2f(hp[c*4]); as += v*sp[c]; ad += v*dp[c]; }
  AS[i] = as; AD[i] = ad;
}

// ---------- CSR build ----------

__global__ void count_k(const int* __restrict__ ei1, const int* __restrict__ ei2,
                        int* __restrict__ CNT){
  int e = blockIdx.x*256 + threadIdx.x;
  if (e >= ETC) return;
  int s, d; edge_sd(e, ei1, ei2, s, d);
  atomicAdd(&CNT[d], 1);
}

__global__ __launch_bounds__(1024) void scan_k(const int* __restrict__ CNT,
                                               int* __restrict__ OFF, int* __restrict__ CUR){
  __shared__ int sums[1024];
  const int t = threadIdx.x;
  const int PER = (NC + 1023)/1024;   // 40
  const int base = t*PER;
  int local = 0;
  for (int i = 0; i < PER; ++i){ int idx = base + i; if (idx < NC) local += CNT[idx]; }
  sums[t] = local;
  __syncthreads();
  for (int off = 1; off < 1024; off <<= 1){
    int v = (t >= off) ? sums[t - off] : 0;
    __syncthreads();
    sums[t] += v;
    __syncthreads();
  }
  int run = (t == 0) ? 0 : sums[t-1];
  for (int i = 0; i < PER; ++i){
    int idx = base + i;
    if (idx < NC){ OFF[idx] = run; CUR[idx] = run; run += CNT[idx]; }
  }
  if (t == 1023) OFF[NC] = sums[1023];
}

__global__ void scatter_k(const int* __restrict__ ei1, const int* __restrict__ ei2,
                          int* __restrict__ CUR, int* __restrict__ ESRC){
  int e = blockIdx.x*256 + threadIdx.x;
  if (e >= ETC) return;
  int s, d; edge_sd(e, ei1, ei2, s, d);
  int pos = atomicAdd(&CUR[d], 1);
  ESRC[pos] = s;
}

// ---------- fused per-dst softmax + aggregation (bf16 H, f32 accum) ----------
// H16 in [n][c][h] bf16; one wave per (dst, 64-channel half); NW = C/64 waves per dst
template<int C, bool RELU>
__global__ __launch_bounds__(256)
void agg_k(const int* __restrict__ OFF, const int* __restrict__ ESRC,
           const float* __restrict__ AS, const float* __restrict__ AD,
           const ushort* __restrict__ H16, const float* __restrict__ bias,
           ushort* __restrict__ Xout){
  constexpr int NW = C/64;
  __shared__ int    sm_s[4][64];
  __shared__ float4 sm_p[4][64];
  const int lane = threadIdx.x & 63;
  const int w    = threadIdx.x >> 6;
  const int g    = blockIdx.x*4 + w;
  const int d    = g / NW;
  const int c    = (NW == 2 ? (g & 1)*64 : 0) + lane;
  const int beg = OFF[d], end = OFF[d+1];
  const float4 ad4 = ((const float4*)AD)[d];

  // pass 1: per-head max over incident edges
  float4 m4 = make_float4(-1e30f, -1e30f, -1e30f, -1e30f);
  for (int i0 = beg; i0 < end; i0 += 64){
    int idx = i0 + lane;
    if (idx < end){
      int s = ESRC[idx];
      float4 a = ((const float4*)AS)[s];
      float4 sc = leaky4(make_float4(a.x+ad4.x, a.y+ad4.y, a.z+ad4.z, a.w+ad4.w));
      m4.x = fmaxf(m4.x, sc.x); m4.y = fmaxf(m4.y, sc.y);
      m4.z = fmaxf(m4.z, sc.z); m4.w = fmaxf(m4.w, sc.w);
    }
  }
  #pragma unroll
  for (int off = 32; off; off >>= 1){
    m4.x = fmaxf(m4.x, __shfl_xor(m4.x, off));
    m4.y = fmaxf(m4.y, __shfl_xor(m4.y, off));
    m4.z = fmaxf(m4.z, __shfl_xor(m4.z, off));
    m4.w = fmaxf(m4.w, __shfl_xor(m4.w, off));
  }

  // pass 2: exp + denom + weighted gather
  float4 den = make_float4(0.f,0.f,0.f,0.f);
  float4 acc = make_float4(0.f,0.f,0.f,0.f);
  for (int i0 = beg; i0 < end; i0 += 64){
    int cnt = min(64, end - i0);
    if (lane < cnt){
      int s = ESRC[i0 + lane];
      float4 a = ((const float4*)AS)[s];
      float4 sc = leaky4(make_float4(a.x+ad4.x, a.y+ad4.y, a.z+ad4.z, a.w+ad4.w));
      float4 p = make_float4(__expf(sc.x - m4.x), __expf(sc.y - m4.y),
                             __expf(sc.z - m4.z), __expf(sc.w - m4.w));
      den.x += p.x; den.y += p.y; den.z += p.z; den.w += p.w;
      sm_s[w][lane] = s;
      sm_p[w][lane] = p;
    }
    __builtin_amdgcn_wave_barrier();
    #pragma unroll 4
    for (int e = 0; e < cnt; ++e){
      int s = sm_s[w][e];
      float4 p = sm_p[w][e];
      uint2 u = *(const uint2*)(H16 + ((long)s*C + c)*4);
      acc.x += p.x*__uint_as_float(u.x << 16);
      acc.y += p.y*__uint_as_float(u.x & 0xffff0000u);
      acc.z += p.z*__uint_as_float(u.y << 16);
      acc.w += p.w*__uint_as_float(u.y & 0xffff0000u);
    }
    __builtin_amdgcn_wave_barrier();
  }

  #pragma unroll
  for (int off = 32; off; off >>= 1){
    den.x += __shfl_xor(den.x, off);
    den.y += __shfl_xor(den.y, off);
    den.z += __shfl_xor(den.z, off);
    den.w += __shfl_xor(den.w, off);
  }
  float4 r = make_float4(1.f/(den.x + 1e-16f), 1.f/(den.y + 1e-16f),
                         1.f/(den.z + 1e-16f), 1.f/(den.w + 1e-16f));
  float o = 0.25f*(acc.x*r.x + acc.y*r.y + acc.z*r.z + acc.w*r.w) + bias[c];
  if (RELU) o = fmaxf(o, 0.f);
  Xout[(long)d*C + c] = f2bu(o);
}

// per output row: L2-normalize h2 row (bf16 in), add residual (f32) + bres
__global__ void final_out_k(const ushort* __restrict__ Hfin, const float* __restrict__ RES,
                            const float* __restrict__ bres, float* __restrict__ out){
  int n = blockIdx.x;
  int lane = threadIdx.x;  // 64
  const ushort* hp = Hfin + (long)(N1C + n)*CINC;
  float v0 = b2f(hp[lane]);
  float v1 = b2f(hp[lane + 64]);
  float ss = v0*v0 + v1*v1;
  #pragma unroll
  for (int off = 32; off; off >>= 1) ss += __shfl_xor(ss, off);
  float inv = 1.f / fmaxf(sqrtf(ss), 1e-12f);
  float* op = out + (long)n*CINC;
  op[lane]      = v0*inv + RES[(long)n*CINC + lane]      + bres[lane];
  op[lane + 64] = v1*inv + RES[(long)n*CINC + lane + 64] + bres[lane + 64];
}

// ---------- launch ----------

extern "C" void kernel_launch(void* const* d_in, const int* in_sizes, int n_in,
                              void* d_out, int out_size, void* d_ws, size_t ws_size,
                              hipStream_t stream) {
  const float* x1  = (const float*)d_in[0];
  const float* x2  = (const float*)d_in[1];
  const int*   ei1 = (const int*)  d_in[2];
  const int*   ei2 = (const int*)  d_in[3];
  const float* W0  = (const float*)d_in[4];
  const float* a0s = (const float*)d_in[5];
  const float* a0d = (const float*)d_in[6];
  const float* b0  = (const float*)d_in[7];
  const float* W1  = (const float*)d_in[8];
  const float* a1s = (const float*)d_in[9];
  const float* a1d = (const float*)d_in[10];
  const float* b1  = (const float*)d_in[11];
  const float* W2  = (const float*)d_in[12];
  const float* a2s = (const float*)d_in[13];
  const float* a2d = (const float*)d_in[14];
  const float* b2  = (const float*)d_in[15];
  const float* Wf  = (const float*)d_in[16];
  const float* afs = (const float*)d_in[17];
  const float* afd = (const float*)d_in[18];
  const float* bf  = (const float*)d_in[19];
  const float* Wres= (const float*)d_in[20];
  const float* bres= (const float*)d_in[21];
  float* out = (float*)d_out;

  char* ws = (char*)d_ws;
  ushort* XA   = (ushort*)(ws + 0);            // 40000*128 bf16 = 10,240,000 B
  ushort* XB   = (ushort*)(ws + 10240000);     // 10,240,000 B
  ushort* H16  = (ushort*)(ws + 20480000);     // 40000*512 bf16 = 40,960,000 B
  float*  RES  = (float*) (ws + 61440000);     // 20000*128 f32 = 10,240,000 B
  float*  AS   = (float*) (ws + 71680000);     // 640,000 B
  float*  AD   = (float*) (ws + 72320000);     // 640,000 B
  int*    OFF  = (int*)   (ws + 72960000);     // 160,064 B
  int*    CUR  = (int*)   (ws + 73120256);     // 160,000 B
  int*    ESRC = (int*)   (ws + 73280256);     // 1,920,000 B
  int*    CNT  = (int*)   (ws + 75200256);     // 160,000 B
  ushort* W0t  = (ushort*)(ws + 75360256);     // 256*128*2 = 65,536
  ushort* W1t  = (ushort*)(ws + 75425792);     // 256*64*2  = 32,768
  ushort* W2t  = (ushort*)(ws + 75458560);     // 512*64*2  = 65,536
  ushort* Wft  = (ushort*)(ws + 75524096);     // 512*128*2 = 131,072
  ushort* Wrt  = (ushort*)(ws + 75655168);     // 128*128*2 = 32,768
  // total ≈ 75.7 MB

  const int EG = (ETC + 255)/256;

  // concat inputs -> XA (bf16)
  concat_x<<<(NC*CINC + 255)/256, 256, 0, stream>>>(x1, x2, XA);

  // CSR build
  hipMemsetAsync(CNT, 0, NC*4, stream);
  count_k<<<EG, 256, 0, stream>>>(ei1, ei2, CNT);
  scan_k<<<1, 1024, 0, stream>>>(CNT, OFF, CUR);
  scatter_k<<<EG, 256, 0, stream>>>(ei1, ei2, CUR, ESRC);

  // transposed (+head-permuted) bf16 weights
  permW_k<<<(128*256 + 255)/256, 256, 0, stream>>>(W0, W0t, 128, 256, 64);
  permW_k<<<( 64*256 + 255)/256, 256, 0, stream>>>(W1, W1t,  64, 256, 64);
  permW_k<<<( 64*512 + 255)/256, 256, 0, stream>>>(W2, W2t,  64, 512, 128);
  permW_k<<<(128*512 + 255)/256, 256, 0, stream>>>(Wf, Wft, 128, 512, 128);
  permW_k<<<(128*128 + 255)/256, 256, 0, stream>>>(Wres, Wrt, 128, 128, 0);

  // residual = x2 @ Wres (f32 out; bres added at the end)
  {
    dim3 g((N2C + 63)/64, 128/64);
    gemm_mfma<128,true><<<g, 256, 0, stream>>>(XA + (long)N1C*CINC, Wrt, nullptr, RES, N2C, 128);
  }

  // ---- layer 0: K=128, C=64, relu ----
  { dim3 g(NC/64, 256/64);
    gemm_mfma<128,false><<<g, 256, 0, stream>>>(XA, W0t, H16, nullptr, NC, 256); }
  att_scores_perm<64><<<(NC*HC + 255)/256, 256, 0, stream>>>(H16, a0s, a0d, AS, AD);
  agg_k<64,true><<<NC/4, 256, 0, stream>>>(OFF, ESRC, AS, AD, H16, b0, XB);

  // ---- layer 1: K=64, C=64, relu ----
  { dim3 g(NC/64, 256/64);
    gemm_mfma<64,false><<<g, 256, 0, stream>>>(XB, W1t, H16, nullptr, NC, 256); }
  att_scores_perm<64><<<(NC*HC + 255)/256, 256, 0, stream>>>(H16, a1s, a1d, AS, AD);
  agg_k<64,true><<<NC/4, 256, 0, stream>>>(OFF, ESRC, AS, AD, H16, b1, XA);

  // ---- layer 2: K=64, C=128, relu ----
  { dim3 g(NC/64, 512/64);
    gemm_mfma<64,false><<<g, 256, 0, stream>>>(XA, W2t, H16, nullptr, NC, 512); }
  att_scores_perm<128><<<(NC*HC + 255)/256, 256, 0, stream>>>(H16, a2s, a2d, AS, AD);
  agg_k<128,true><<<NC/2, 256, 0, stream>>>(OFF, ESRC, AS, AD, H16, b2, XB);

  // ---- layer f: K=128, C=128, no relu ----
  { dim3 g(NC/64, 512/64);
    gemm_mfma<128,false><<<g, 256, 0, stream>>>(XB, Wft, H16, nullptr, NC, 512); }
  att_scores_perm<128><<<(NC*HC + 255)/256, 256, 0, stream>>>(H16, afs, afd, AS, AD);
  agg_k<128,false><<<NC/2, 256, 0, stream>>>(OFF, ESRC, AS, AD, H16, bf, XA);

  // ---- output: norm(h2) + residual ----
  final_out_k<<<N2C, 64, 0, stream>>>(XA, RES, bres, out);
}

// Round 4
// 526.706 us; speedup vs baseline: 3.5973x; 1.2036x over previous
//
#include <hip/hip_runtime.h>
#include <hip/hip_bf16.h>

#define N1C 20000
#define N2C 20000
#define NC  40000           // N1C + N2C
#define EC  160000
#define ETC 480000          // 3*EC
#define CINC 128
#define HC 4
#define NBLK 157            // ceil(NC/256)

typedef __attribute__((ext_vector_type(8))) short short8v;
typedef __attribute__((ext_vector_type(4))) float f32x4;

__device__ __forceinline__ ushort f2bu(float f){
  __hip_bfloat16 h = __float2bfloat16(f);
  union { __hip_bfloat16 b; ushort u; } v; v.b = h; return v.u;
}
__device__ __forceinline__ float b2f(ushort u){
  return __uint_as_float(((unsigned)u) << 16);
}

// decode edge e of the concatenated edge list into (src,dst)
__device__ __forceinline__ void edge_sd(int e, const int* __restrict__ ei1,
                                        const int* __restrict__ ei2, int& s, int& d){
  if (e < EC)            { s = ei1[e];           d = ei1[EC + e]; }
  else if (e < 2*EC)     { int t = e - EC;   s = ei2[t] + N1C;  d = ei2[EC + t] + N1C; }
  else                   { int t = e - 2*EC; s = ei1[t] + N1C;  d = ei1[EC + t] + N1C; }
}

__device__ __forceinline__ float4 leaky4(float4 v){
  v.x = v.x > 0.f ? v.x : 0.2f*v.x;
  v.y = v.y > 0.f ? v.y : 0.2f*v.y;
  v.z = v.z > 0.f ? v.z : 0.2f*v.z;
  v.w = v.w > 0.f ? v.w : 0.2f*v.w;
  return v;
}

// ---------- input prep ----------

__global__ void concat_x(const float* __restrict__ x1, const float* __restrict__ x2,
                         ushort* __restrict__ X){
  int i = blockIdx.x*256 + threadIdx.x;
  if (i >= NC*CINC) return;
  float v = (i < N1C*CINC) ? x1[i] : x2[i - N1C*CINC];
  X[i] = f2bu(v);
}

// Wt[m][k] (bf16) = W[k][perm(m)]; perm(m) = (m&3)*Ch + (m>>2) if Ch>0 else m
__global__ void permW_k(const float* __restrict__ W, ushort* __restrict__ Wt,
                        int K, int M, int Ch){
  int i = blockIdx.x*256 + threadIdx.x;
  if (i >= K*M) return;
  int m = i / K, k = i - m*K;
  int col = Ch ? ((m & 3)*Ch + (m >> 2)) : m;
  Wt[i] = f2bu(W[k*M + col]);
}

// ---------- MFMA GEMM: H[n][m] = sum_k X[n][k] * Wt[m][k] ----------
template<int K, bool F32OUT>
__global__ __launch_bounds__(256)
void gemm_mfma(const ushort* __restrict__ X, const ushort* __restrict__ Wt,
               ushort* __restrict__ Hout, float* __restrict__ HoutF, int nrows, int M){
  __shared__ float st[4][16][68];
  const int lane = threadIdx.x & 63;
  const int w    = threadIdx.x >> 6;
  const int n0   = blockIdx.x*64 + w*16;
  const int m0   = blockIdx.y*64;
  const int hi = lane >> 4;      // 0..3
  const int lo = lane & 15;      // 0..15
  int ra = n0 + lo; if (ra >= nrows) ra = nrows - 1;   // clamp (load safety)
  const ushort* ap = X + (long)ra*K + hi*8;

  f32x4 acc[4];
  #pragma unroll
  for (int t = 0; t < 4; ++t) acc[t] = (f32x4){0.f,0.f,0.f,0.f};

  #pragma unroll
  for (int k0 = 0; k0 < K; k0 += 32){
    short8v a = *(const short8v*)(ap + k0);
    #pragma unroll
    for (int t = 0; t < 4; ++t){
      short8v b = *(const short8v*)(Wt + (long)(m0 + t*16 + lo)*K + k0 + hi*8);
      acc[t] = __builtin_amdgcn_mfma_f32_16x16x32_bf16(a, b, acc[t], 0, 0, 0);
    }
  }
  #pragma unroll
  for (int t = 0; t < 4; ++t)
    #pragma unroll
    for (int j = 0; j < 4; ++j)
      st[w][hi*4 + j][t*16 + lo] = acc[t][j];
  __builtin_amdgcn_wave_barrier();

  const int row = lane >> 2, cg = lane & 3;
  if (n0 + row < nrows){
    if (F32OUT){
      float* op = HoutF + (long)(n0 + row)*M + m0 + cg*16;
      #pragma unroll
      for (int q = 0; q < 4; ++q)
        *(float4*)(op + q*4) = *(float4*)&st[w][row][cg*16 + q*4];
    } else {
      ushort* op = Hout + (long)(n0 + row)*M + m0 + cg*16;
      #pragma unroll
      for (int q = 0; q < 4; ++q){
        float4 v = *(float4*)&st[w][row][cg*16 + q*4];
        ushort4 u; u.x = f2bu(v.x); u.y = f2bu(v.y); u.z = f2bu(v.z); u.w = f2bu(v.w);
        *(ushort4*)(op + q*4) = u;
      }
    }
  }
}

// ---------- attention scores: wave per node, lane = channel ----------
// AS[n,h] = sum_c H[n,c,h]*att_s[h,c]  (H bf16 in [n][c][h] layout)
template<int C>
__global__ __launch_bounds__(256)
void att_scores_w(const ushort* __restrict__ H16, const float* __restrict__ att_s,
                  const float* __restrict__ att_d, float* __restrict__ AS,
                  float* __restrict__ AD){
  const int lane = threadIdx.x & 63;
  const int w    = threadIdx.x >> 6;
  const int n    = blockIdx.x*4 + w;          // NC divisible by 4
  const ushort* hp = H16 + (long)n*(HC*C);
  float as0=0.f, as1=0.f, as2=0.f, as3=0.f;
  float ad0=0.f, ad1=0.f, ad2=0.f, ad3=0.f;
  #pragma unroll
  for (int j = 0; j < C/64; ++j){
    int c = lane + j*64;
    uint2 u = *(const uint2*)(hp + c*4);
    float h0 = __uint_as_float(u.x << 16);
    float h1 = __uint_as_float(u.x & 0xffff0000u);
    float h2 = __uint_as_float(u.y << 16);
    float h3 = __uint_as_float(u.y & 0xffff0000u);
    as0 += h0*att_s[0*C + c]; ad0 += h0*att_d[0*C + c];
    as1 += h1*att_s[1*C + c]; ad1 += h1*att_d[1*C + c];
    as2 += h2*att_s[2*C + c]; ad2 += h2*att_d[2*C + c];
    as3 += h3*att_s[3*C + c]; ad3 += h3*att_d[3*C + c];
  }
  #pragma unroll
  for (int off = 32; off; off >>= 1){
    as0 += __shfl_xor(as0, off); ad0 += __shfl_xor(ad0, off);
    as1 += __shfl_xor(as1, off); ad1 += __shfl_xor(ad1, off);
    as2 += __shfl_xor(as2, off); ad2 += __shfl_xor(ad2, off);
    as3 += __shfl_xor(as3, off); ad3 += __shfl_xor(ad3, off);
  }
  if (lane == 0){
    ((float4*)AS)[n] = make_float4(as0, as1, as2, as3);
    ((float4*)AD)[n] = make_float4(ad0, ad1, ad2, ad3);
  }
}

// ---------- CSR build ----------

__global__ void count_k(const int* __restrict__ ei1, const int* __restrict__ ei2,
                        int* __restrict__ CNT){
  int e = blockIdx.x*256 + threadIdx.x;
  if (e >= ETC) return;
  int s, d; edge_sd(e, ei1, ei2, s, d);
  atomicAdd(&CNT[d], 1);
}

// hierarchical scan: (A) per-block exclusive scan + block sums
__global__ __launch_bounds__(256) void scan_blk_k(const int* __restrict__ CNT,
                                                  int* __restrict__ EXC,
                                                  int* __restrict__ BSUM){
  __shared__ int s[256];
  const int t = threadIdx.x, b = blockIdx.x;
  const int i = b*256 + t;
  int v = (i < NC) ? CNT[i] : 0;
  s[t] = v;
  __syncthreads();
  #pragma unroll
  for (int off = 1; off < 256; off <<= 1){
    int u = (t >= off) ? s[t - off] : 0;
    __syncthreads();
    s[t] += u;
    __syncthreads();
  }
  if (i < NC) EXC[i] = s[t] - v;
  if (t == 255) BSUM[b] = s[255];
}

// (B) single-block scan of the 157 block sums
__global__ __launch_bounds__(256) void scan_top_k(const int* __restrict__ BSUM,
                                                  int* __restrict__ BOFF){
  __shared__ int s[256];
  const int t = threadIdx.x;
  int v = (t < NBLK) ? BSUM[t] : 0;
  s[t] = v;
  __syncthreads();
  #pragma unroll
  for (int off = 1; off < 256; off <<= 1){
    int u = (t >= off) ? s[t - off] : 0;
    __syncthreads();
    s[t] += u;
    __syncthreads();
  }
  if (t < NBLK) BOFF[t] = s[t] - v;
}

// (C) combine
__global__ __launch_bounds__(256) void scan_add_k(const int* __restrict__ EXC,
                                                  const int* __restrict__ BOFF,
                                                  int* __restrict__ OFF,
                                                  int* __restrict__ CUR){
  int i = blockIdx.x*256 + threadIdx.x;
  if (i < NC){ int o = EXC[i] + BOFF[i >> 8]; OFF[i] = o; CUR[i] = o; }
  if (i == NC) OFF[NC] = ETC;
}

__global__ void scatter_k(const int* __restrict__ ei1, const int* __restrict__ ei2,
                          int* __restrict__ CUR, int* __restrict__ ESRC){
  int e = blockIdx.x*256 + threadIdx.x;
  if (e >= ETC) return;
  int s, d; edge_sd(e, ei1, ei2, s, d);
  int pos = atomicAdd(&CUR[d], 1);
  ESRC[pos] = s;
}

// ---------- fused per-dst softmax + aggregation (bf16 H, f32 accum) ----------
template<int C, bool RELU>
__global__ __launch_bounds__(256)
void agg_k(const int* __restrict__ OFF, const int* __restrict__ ESRC,
           const float* __restrict__ AS, const float* __restrict__ AD,
           const ushort* __restrict__ H16, const float* __restrict__ bias,
           ushort* __restrict__ Xout){
  constexpr int NW = C/64;
  __shared__ int    sm_s[4][64];
  __shared__ float4 sm_p[4][64];
  const int lane = threadIdx.x & 63;
  const int w    = threadIdx.x >> 6;
  const int g    = blockIdx.x*4 + w;
  const int d    = g / NW;
  const int c    = (NW == 2 ? (g & 1)*64 : 0) + lane;
  const int beg = OFF[d], end = OFF[d+1];
  const float4 ad4 = ((const float4*)AD)[d];

  // pass 1: per-head max
  float4 m4 = make_float4(-1e30f, -1e30f, -1e30f, -1e30f);
  for (int i0 = beg; i0 < end; i0 += 64){
    int idx = i0 + lane;
    if (idx < end){
      int s = ESRC[idx];
      float4 a = ((const float4*)AS)[s];
      float4 sc = leaky4(make_float4(a.x+ad4.x, a.y+ad4.y, a.z+ad4.z, a.w+ad4.w));
      m4.x = fmaxf(m4.x, sc.x); m4.y = fmaxf(m4.y, sc.y);
      m4.z = fmaxf(m4.z, sc.z); m4.w = fmaxf(m4.w, sc.w);
    }
  }
  #pragma unroll
  for (int off = 32; off; off >>= 1){
    m4.x = fmaxf(m4.x, __shfl_xor(m4.x, off));
    m4.y = fmaxf(m4.y, __shfl_xor(m4.y, off));
    m4.z = fmaxf(m4.z, __shfl_xor(m4.z, off));
    m4.w = fmaxf(m4.w, __shfl_xor(m4.w, off));
  }

  // pass 2: exp + denom + weighted gather
  float4 den = make_float4(0.f,0.f,0.f,0.f);
  float4 acc = make_float4(0.f,0.f,0.f,0.f);
  for (int i0 = beg; i0 < end; i0 += 64){
    int cnt = min(64, end - i0);
    if (lane < cnt){
      int s = ESRC[i0 + lane];
      float4 a = ((const float4*)AS)[s];
      float4 sc = leaky4(make_float4(a.x+ad4.x, a.y+ad4.y, a.z+ad4.z, a.w+ad4.w));
      float4 p = make_float4(__expf(sc.x - m4.x), __expf(sc.y - m4.y),
                             __expf(sc.z - m4.z), __expf(sc.w - m4.w));
      den.x += p.x; den.y += p.y; den.z += p.z; den.w += p.w;
      sm_s[w][lane] = s;
      sm_p[w][lane] = p;
    }
    __builtin_amdgcn_wave_barrier();
    #pragma unroll 4
    for (int e = 0; e < cnt; ++e){
      int s = sm_s[w][e];
      float4 p = sm_p[w][e];
      uint2 u = *(const uint2*)(H16 + ((long)s*C + c)*4);
      acc.x += p.x*__uint_as_float(u.x << 16);
      acc.y += p.y*__uint_as_float(u.x & 0xffff0000u);
      acc.z += p.z*__uint_as_float(u.y << 16);
      acc.w += p.w*__uint_as_float(u.y & 0xffff0000u);
    }
    __builtin_amdgcn_wave_barrier();
  }

  #pragma unroll
  for (int off = 32; off; off >>= 1){
    den.x += __shfl_xor(den.x, off);
    den.y += __shfl_xor(den.y, off);
    den.z += __shfl_xor(den.z, off);
    den.w += __shfl_xor(den.w, off);
  }
  float4 r = make_float4(1.f/(den.x + 1e-16f), 1.f/(den.y + 1e-16f),
                         1.f/(den.z + 1e-16f), 1.f/(den.w + 1e-16f));
  float o = 0.25f*(acc.x*r.x + acc.y*r.y + acc.z*r.z + acc.w*r.w) + bias[c];
  if (RELU) o = fmaxf(o, 0.f);
  Xout[(long)d*C + c] = f2bu(o);
}

// per output row: L2-normalize h2 row (bf16 in), add residual (f32) + bres
__global__ void final_out_k(const ushort* __restrict__ Hfin, const float* __restrict__ RES,
                            const float* __restrict__ bres, float* __restrict__ out){
  int n = blockIdx.x;
  int lane = threadIdx.x;  // 64
  const ushort* hp = Hfin + (long)(N1C + n)*CINC;
  float v0 = b2f(hp[lane]);
  float v1 = b2f(hp[lane + 64]);
  float ss = v0*v0 + v1*v1;
  #pragma unroll
  for (int off = 32; off; off >>= 1) ss += __shfl_xor(ss, off);
  float inv = 1.f / fmaxf(sqrtf(ss), 1e-12f);
  float* op = out + (long)n*CINC;
  op[lane]      = v0*inv + RES[(long)n*CINC + lane]      + bres[lane];
  op[lane + 64] = v1*inv + RES[(long)n*CINC + lane + 64] + bres[lane + 64];
}

// ---------- launch ----------

extern "C" void kernel_launch(void* const* d_in, const int* in_sizes, int n_in,
                              void* d_out, int out_size, void* d_ws, size_t ws_size,
                              hipStream_t stream) {
  const float* x1  = (const float*)d_in[0];
  const float* x2  = (const float*)d_in[1];
  const int*   ei1 = (const int*)  d_in[2];
  const int*   ei2 = (const int*)  d_in[3];
  const float* W0  = (const float*)d_in[4];
  const float* a0s = (const float*)d_in[5];
  const float* a0d = (const float*)d_in[6];
  const float* b0  = (const float*)d_in[7];
  const float* W1  = (const float*)d_in[8];
  const float* a1s = (const float*)d_in[9];
  const float* a1d = (const float*)d_in[10];
  const float* b1  = (const float*)d_in[11];
  const float* W2  = (const float*)d_in[12];
  const float* a2s = (const float*)d_in[13];
  const float* a2d = (const float*)d_in[14];
  const float* b2  = (const float*)d_in[15];
  const float* Wf  = (const float*)d_in[16];
  const float* afs = (const float*)d_in[17];
  const float* afd = (const float*)d_in[18];
  const float* bf  = (const float*)d_in[19];
  const float* Wres= (const float*)d_in[20];
  const float* bres= (const float*)d_in[21];
  float* out = (float*)d_out;

  char* ws = (char*)d_ws;
  ushort* XA   = (ushort*)(ws + 0);            // 10,240,000 B
  ushort* XB   = (ushort*)(ws + 10240000);     // 10,240,000 B
  ushort* H16  = (ushort*)(ws + 20480000);     // 40,960,000 B
  float*  RES  = (float*) (ws + 61440000);     // 10,240,000 B
  float*  AS   = (float*) (ws + 71680000);     // 640,000 B
  float*  AD   = (float*) (ws + 72320000);     // 640,000 B
  int*    OFF  = (int*)   (ws + 72960000);     // 160,064 B
  int*    CUR  = (int*)   (ws + 73120256);     // 160,000 B
  int*    ESRC = (int*)   (ws + 73280256);     // 1,920,000 B
  int*    CNT  = (int*)   (ws + 75200256);     // 160,000 B
  ushort* W0t  = (ushort*)(ws + 75360256);
  ushort* W1t  = (ushort*)(ws + 75425792);
  ushort* W2t  = (ushort*)(ws + 75458560);
  ushort* Wft  = (ushort*)(ws + 75524096);
  ushort* Wrt  = (ushort*)(ws + 75655168);
  int*    EXC  = (int*)   (ws + 75687936);     // 160,000 B
  int*    BSUM = (int*)   (ws + 75847936);     // 1,024 B
  int*    BOFF = (int*)   (ws + 75848960);     // 1,024 B
  // total ≈ 75.85 MB

  const int EG = (ETC + 255)/256;

  // concat inputs -> XA (bf16)
  concat_x<<<(NC*CINC + 255)/256, 256, 0, stream>>>(x1, x2, XA);

  // CSR build (parallel scan)
  hipMemsetAsync(CNT, 0, NC*4, stream);
  count_k<<<EG, 256, 0, stream>>>(ei1, ei2, CNT);
  scan_blk_k<<<NBLK, 256, 0, stream>>>(CNT, EXC, BSUM);
  scan_top_k<<<1, 256, 0, stream>>>(BSUM, BOFF);
  scan_add_k<<<NBLK, 256, 0, stream>>>(EXC, BOFF, OFF, CUR);
  scatter_k<<<EG, 256, 0, stream>>>(ei1, ei2, CUR, ESRC);

  // transposed (+head-permuted) bf16 weights
  permW_k<<<(128*256 + 255)/256, 256, 0, stream>>>(W0, W0t, 128, 256, 64);
  permW_k<<<( 64*256 + 255)/256, 256, 0, stream>>>(W1, W1t,  64, 256, 64);
  permW_k<<<( 64*512 + 255)/256, 256, 0, stream>>>(W2, W2t,  64, 512, 128);
  permW_k<<<(128*512 + 255)/256, 256, 0, stream>>>(Wf, Wft, 128, 512, 128);
  permW_k<<<(128*128 + 255)/256, 256, 0, stream>>>(Wres, Wrt, 128, 128, 0);

  // residual = x2 @ Wres (f32 out; bres added at the end)
  {
    dim3 g((N2C + 63)/64, 128/64);
    gemm_mfma<128,true><<<g, 256, 0, stream>>>(XA + (long)N1C*CINC, Wrt, nullptr, RES, N2C, 128);
  }

  // ---- layer 0: K=128, C=64, relu ----
  { dim3 g(NC/64, 256/64);
    gemm_mfma<128,false><<<g, 256, 0, stream>>>(XA, W0t, H16, nullptr, NC, 256); }
  att_scores_w<64><<<NC/4, 256, 0, stream>>>(H16, a0s, a0d, AS, AD);
  agg_k<64,true><<<NC/4, 256, 0, stream>>>(OFF, ESRC, AS, AD, H16, b0, XB);

  // ---- layer 1: K=64, C=64, relu ----
  { dim3 g(NC/64, 256/64);
    gemm_mfma<64,false><<<g, 256, 0, stream>>>(XB, W1t, H16, nullptr, NC, 256); }
  att_scores_w<64><<<NC/4, 256, 0, stream>>>(H16, a1s, a1d, AS, AD);
  agg_k<64,true><<<NC/4, 256, 0, stream>>>(OFF, ESRC, AS, AD, H16, b1, XA);

  // ---- layer 2: K=64, C=128, relu ----
  { dim3 g(NC/64, 512/64);
    gemm_mfma<64,false><<<g, 256, 0, stream>>>(XA, W2t, H16, nullptr, NC, 512); }
  att_scores_w<128><<<NC/4, 256, 0, stream>>>(H16, a2s, a2d, AS, AD);
  agg_k<128,true><<<NC/2, 256, 0, stream>>>(OFF, ESRC, AS, AD, H16, b2, XB);

  // ---- layer f: K=128, C=128, no relu ----
  { dim3 g(NC/64, 512/64);
    gemm_mfma<128,false><<<g, 256, 0, stream>>>(XB, Wft, H16, nullptr, NC, 512); }
  att_scores_w<128><<<NC/4, 256, 0, stream>>>(H16, afs, afd, AS, AD);
  agg_k<128,false><<<NC/2, 256, 0, stream>>>(OFF, ESRC, AS, AD, H16, bf, XA);

  // ---- output: norm(h2) + residual ----
  final_out_k<<<N2C, 64, 0, stream>>>(XA, RES, bres, out);
}